// Round 1
// baseline (1927.959 us; speedup 1.0000x reference)
//
#include <hip/hip_runtime.h>
#include <hip/hip_bf16.h>
#include <stdint.h>

// Problem constants
#define NN 8
#define CI 128
#define CO 128
#define LL 2048
#define VV 25
#define PP 3
#define CW 3200        // CO*VV
#define KK 384         // PP*CI
#define BN_EPS 1e-5f

// ws byte offsets
#define AW_OFF    0u           // Aw f32 [3][25][28]  (2100 f32)
#define W2_OFF    16384u       // W2 f32 [384][128]
#define ST_OFF    262144u      // stats f32 [256] (sum[128], sumsq[128])
#define SS_OFF    266240u      // scale[128], shift[128]
#define Z_OFF     (1u<<20)     // z   bf16 [N][L][3200]  (104,857,600 B)
#define ACC_OFF   (Z_OFF + 104857600u)  // acc bf16 same size

typedef __hip_bfloat16 bf16;

__device__ __forceinline__ float bf2f(bf16 v) { return __bfloat162float(v); }
__device__ __forceinline__ float us2f(uint16_t u) {
    return __uint_as_float(((uint32_t)u) << 16);
}

// ---------------- K0: prep (Aw fold, W2 permuted transpose, zero stats) ----
__global__ void k0_prep(const float* __restrict__ A, const float* __restrict__ EI,
                        const float* __restrict__ W, float* __restrict__ ws_f)
{
    int i = blockIdx.x * 256 + threadIdx.x;
    float* Aw = ws_f + AW_OFF / 4;
    float* W2 = ws_f + W2_OFF / 4;
    float* st = ws_f + ST_OFF / 4;
    if (i < 2100) {   // [3][25][28], zero-padded w>=25
        int p = i / 700; int r = i - p * 700; int v = r / 28; int w = r - v * 28;
        float val = 0.f;
        if (w < 25) val = A[(p * 25 + v) * 25 + w] * EI[v * 25 + w];
        Aw[i] = val;
    }
    int j = i - 2100;
    if (j >= 0 && j < KK * 128) {   // W2[k = p*128+ci][c] = W[(p*128+c)*128 + ci]
        int k = j >> 7, c = j & 127;
        int p = k >> 7, ci = k & 127;
        W2[j] = W[(size_t)((p << 7) + c) * 128 + ci];
    }
    int s = i - (2100 + KK * 128);
    if (s >= 0 && s < 256) st[s] = 0.f;   // zero the atomic stats accumulators
}

// ---------------- K1: fused spatial conv + 1x1-conv GEMM  ------------------
// One block per (n,l).  z[c,w] = sum_k W2[k][c] * XA[k][w],  k=(p,ci), K=384.
__launch_bounds__(256, 2)
__global__ void k1_gemm(const float* __restrict__ x, const float* __restrict__ ws_f,
                        bf16* __restrict__ z)
{
    const int l = blockIdx.x, n = blockIdx.y;
    const int tid = threadIdx.x;
    __shared__ float Xs[CI * VV];      // 12800 B  [ci][v] (stride 25, odd -> no conflicts)
    __shared__ float XAs[KK * 32];     // 49152 B  [k][w-pad32]
    __shared__ float Aws[2100];        // 8400 B   [p][v][28]
    __shared__ float W2s[16 * 128];    // 8192 B   staged K-chunk
    const float* Awg = ws_f + AW_OFF / 4;
    const float* W2g = ws_f + W2_OFF / 4;

    for (int i = tid; i < 2100; i += 256) Aws[i] = Awg[i];
    for (int i = tid; i < CI * VV; i += 256) {
        int ci = i / 25, v = i - ci * 25;
        Xs[i] = x[(((size_t)n * CI + ci) * LL + l) * VV + v];
    }
    __syncthreads();

    // Build XA: threads 0..191 each handle slots q=2t, 2t+1 (same p always).
    if (tid < 192) {
        int q0 = tid * 2;
        int p = q0 >> 7;
        int ci0 = q0 & 127;
        float acc0[25], acc1[25];
        #pragma unroll
        for (int w = 0; w < 25; w++) { acc0[w] = 0.f; acc1[w] = 0.f; }
        const float* awbase = &Aws[p * 700];
        for (int v = 0; v < 25; v++) {
            float x0 = Xs[ci0 * 25 + v];
            float x1 = Xs[(ci0 + 1) * 25 + v];
            const float* ar = awbase + v * 28;
            float aw[28];
            #pragma unroll
            for (int t4 = 0; t4 < 7; t4++) {
                float4 f = *(const float4*)(ar + t4 * 4);
                aw[t4*4+0] = f.x; aw[t4*4+1] = f.y; aw[t4*4+2] = f.z; aw[t4*4+3] = f.w;
            }
            #pragma unroll
            for (int w = 0; w < 25; w++) {
                acc0[w] = fmaf(x0, aw[w], acc0[w]);
                acc1[w] = fmaf(x1, aw[w], acc1[w]);
            }
        }
        #pragma unroll
        for (int w = 0; w < 25; w++) {
            XAs[q0 * 32 + w] = acc0[w];
            XAs[(q0 + 1) * 32 + w] = acc1[w];
        }
        #pragma unroll
        for (int w = 25; w < 32; w++) {
            XAs[q0 * 32 + w] = 0.f;
            XAs[(q0 + 1) * 32 + w] = 0.f;
        }
    }
    __syncthreads();

    // GEMM: 32 c-groups x 8 w-groups, 4x4 per thread, K staged in 16-chunks.
    const int cg = tid & 31, wg = tid >> 5;
    const int c0 = cg * 4, w0 = wg * 4;
    float acc[4][4] = {};
    for (int ph = 0; ph < 24; ph++) {
        {   // stage W2 rows [ph*16, ph*16+16)
            const float4* src = (const float4*)(W2g + ph * 16 * 128);
            float4* dst = (float4*)W2s;
            dst[tid] = src[tid];
            dst[tid + 256] = src[tid + 256];
        }
        __syncthreads();
        #pragma unroll
        for (int kk = 0; kk < 16; kk++) {
            float4 wv = *(const float4*)&W2s[kk * 128 + c0];
            float4 xv = *(const float4*)&XAs[(ph * 16 + kk) * 32 + w0];
            float wva[4] = {wv.x, wv.y, wv.z, wv.w};
            float xva[4] = {xv.x, xv.y, xv.z, xv.w};
            #pragma unroll
            for (int i = 0; i < 4; i++)
                #pragma unroll
                for (int j = 0; j < 4; j++)
                    acc[i][j] = fmaf(wva[i], xva[j], acc[i][j]);
        }
        __syncthreads();
    }

    // Store z tile (bf16), layout [n][l][c*25+w] -> contiguous 6.4KB per block
    bf16* zp = z + ((size_t)(n * LL) + l) * CW;
    #pragma unroll
    for (int i = 0; i < 4; i++) {
        int c = c0 + i;
        #pragma unroll
        for (int j = 0; j < 4; j++) {
            int w = w0 + j;
            if (w < 25) zp[c * 25 + w] = __float2bfloat16(acc[i][j]);
        }
    }
}

// ---------------- K2: causal 9-tap temporal window + BN partial stats ------
__launch_bounds__(256, 4)
__global__ void k2_toep(const bf16* __restrict__ z, bf16* __restrict__ acc,
                        float* __restrict__ stats)
{
    const int n = blockIdx.y, l0 = blockIdx.x * 16;
    const int tid = threadIdx.x;
    __shared__ float ssum[128], ssq[128];
    if (tid < 128) { ssum[tid] = 0.f; ssq[tid] = 0.f; }
    __syncthreads();
    const bf16* zn = z + (size_t)n * LL * CW;
    bf16* an = acc + (size_t)n * LL * CW;
    float run[13], ps[13], pq[13];
    #pragma unroll
    for (int k = 0; k < 13; k++) { run[k] = 0.f; ps[k] = 0.f; pq[k] = 0.f; }
    // init window with halo l0-8 .. l0-1 (zero-padded below 0)
    for (int h = 8; h >= 1; h--) {
        int lp = l0 - h;
        if (lp >= 0) {
            #pragma unroll
            for (int k = 0; k < 13; k++) {
                int pos = tid + k * 256;
                if (pos < CW) run[k] += bf2f(zn[(size_t)lp * CW + pos]);
            }
        }
    }
    for (int il = 0; il < 16; il++) {
        int l = l0 + il;
        bool dosub = (il >= 1) && (l >= 9);
        #pragma unroll
        for (int k = 0; k < 13; k++) {
            int pos = tid + k * 256;
            if (pos < CW) {
                float r = run[k] + bf2f(zn[(size_t)l * CW + pos]);
                if (dosub) r -= bf2f(zn[(size_t)(l - 9) * CW + pos]);
                run[k] = r;
                ps[k] += r;
                pq[k] += r * r;
                an[(size_t)l * CW + pos] = __float2bfloat16(r);
            }
        }
    }
    #pragma unroll
    for (int k = 0; k < 13; k++) {
        int pos = tid + k * 256;
        if (pos < CW) {
            int c = pos / 25;
            atomicAdd(&ssum[c], ps[k]);
            atomicAdd(&ssq[c], pq[k]);
        }
    }
    __syncthreads();
    if (tid < 128) {
        atomicAdd(&stats[tid], ssum[tid]);
        atomicAdd(&stats[128 + tid], ssq[tid]);
    }
}

// ---------------- K2b: per-channel scale/shift -----------------------------
__global__ void k2b_stats(const float* __restrict__ stats, const float* __restrict__ gamma,
                          const float* __restrict__ beta, float* __restrict__ ss)
{
    int c = threadIdx.x;
    if (c < 128) {
        const float cnt = (float)(NN * LL * VV);
        float mean = stats[c] / cnt;
        float var = stats[128 + c] / cnt - mean * mean;
        float sc = gamma[c] * rsqrtf(var + BN_EPS);
        float sh = beta[c] - mean * sc;
        ss[c] = sc;
        ss[128 + c] = sh;
    }
}

// ---------------- K3: BN + ReLU + residual + ReLU (LDS transpose) ----------
__launch_bounds__(256, 2)
__global__ void k3_out(const bf16* __restrict__ acc, const float* __restrict__ x,
                       const float* __restrict__ ss, float* __restrict__ out)
{
    const int lt = blockIdx.x;   // 64 l-tiles of 32
    const int ct = blockIdx.y;   // 4  c-tiles of 32
    const int n  = blockIdx.z;
    const int tid = threadIdx.x;
    const int l0 = lt * 32, c0 = ct * 32;
    __shared__ uint16_t accs[25600];   // [cl][r][w] = cl*800 + r*25 + w
    __shared__ float scs[32], shs[32];
    if (tid < 32) { scs[tid] = ss[c0 + tid]; shs[tid] = ss[128 + c0 + tid]; }
    const uint32_t* ab = (const uint32_t*)acc;
    for (int e = tid; e < 12800; e += 256) {
        int r = e / 400, q = e - r * 400;
        uint32_t d = ab[(size_t)(n * LL + l0 + r) * 1600 + (c0 * 25) / 2 + q];
        int pp = q * 2;
        int cl = pp / 25, w = pp - cl * 25;
        accs[cl * 800 + r * 25 + w] = (uint16_t)(d & 0xffffu);
        if (w + 1 < 25) accs[cl * 800 + r * 25 + w + 1] = (uint16_t)(d >> 16);
        else            accs[(cl + 1) * 800 + r * 25 + 0] = (uint16_t)(d >> 16);
    }
    __syncthreads();

    const size_t obase = ((size_t)(n * CO + c0) * LL + l0) * VV;
    for (int it = tid; it < 6400; it += 256) {
        int oc = it / 200;
        int r2 = (it - oc * 200) * 4;   // flat (ol*25+v), multiple of 4
        ushort4 av = *(const ushort4*)&accs[oc * 800 + r2];
        size_t ga = obase + (size_t)oc * (LL * VV) + r2;
        float4 xv = *(const float4*)(x + ga);
        float sc = scs[oc], sh = shs[oc];
        float4 o;
        o.x = fmaxf(fmaxf(fmaf(sc, us2f(av.x), sh), 0.f) + xv.x, 0.f);
        o.y = fmaxf(fmaxf(fmaf(sc, us2f(av.y), sh), 0.f) + xv.y, 0.f);
        o.z = fmaxf(fmaxf(fmaf(sc, us2f(av.z), sh), 0.f) + xv.z, 0.f);
        o.w = fmaxf(fmaxf(fmaf(sc, us2f(av.w), sh), 0.f) + xv.w, 0.f);
        *(float4*)(out + ga) = o;
    }
}

extern "C" void kernel_launch(void* const* d_in, const int* in_sizes, int n_in,
                              void* d_out, int out_size, void* d_ws, size_t ws_size,
                              hipStream_t stream)
{
    const float* x  = (const float*)d_in[0];
    const float* A  = (const float*)d_in[1];
    const float* EI = (const float*)d_in[2];
    const float* W  = (const float*)d_in[3];
    const float* ga = (const float*)d_in[4];
    const float* be = (const float*)d_in[5];
    float* out = (float*)d_out;
    char*  ws  = (char*)d_ws;
    float* ws_f = (float*)ws;
    bf16*  z    = (bf16*)(ws + Z_OFF);
    bf16*  acc  = (bf16*)(ws + ACC_OFF);
    float* stats = (float*)(ws + ST_OFF);
    float* ssbuf = (float*)(ws + SS_OFF);

    k0_prep<<<256, 256, 0, stream>>>(A, EI, W, ws_f);
    k1_gemm<<<dim3(LL, NN), 256, 0, stream>>>(x, ws_f, z);
    k2_toep<<<dim3(LL / 16, NN), 256, 0, stream>>>(z, acc, stats);
    k2b_stats<<<1, 128, 0, stream>>>(stats, ga, be, ssbuf);
    k3_out<<<dim3(64, 4, NN), 256, 0, stream>>>(acc, x, ssbuf, out);
}